// Round 8
// baseline (262.900 us; speedup 1.0000x reference)
//
#include <hip/hip_runtime.h>

// ---------------------------------------------------------------------------
// SGC: out[b,i,f] = sum_{j!=i} (adj^4)[i,j] * rm[b,j,f]
//   A2   = adj @ adj          (MX-fp8 e4m3 MFMA K=128, 4096^3, const scale)
//   T1T  = gemm(A=RMT, BT=A2) (split-K, 2048 blocks, bf16 partials, direct
//                              transposed layout -> coalesced flat reduce)
//   out  = gemm(A=A2, BT=T1T) - d*rm  (split-K, bf16 partials, fused reduce)
//   d[i] = sum_j A2[i,j]*A2[j,i]
// Lessons encoded:
//  - LDS-free fragment-direct skinny GEMM regressed 2x (r6): keep LDS staging.
//  - fp8 LDS conflicts (8.39e6) are structural, invariant under chunk
//    permutation, NOT the critical pipe (r5): big GEMM LDS scheme frozen.
//  - Same-address split-K atomics regressed (r3): explicit partials.
//  - Skinny split-K is latency-bound; dbuf prefetch hides only the ~77cy
//    compute phase (r7): scale block count (KC=256 -> 2048 blocks) for TLP.
// ---------------------------------------------------------------------------

typedef __attribute__((ext_vector_type(8))) __bf16 bf16x8;
typedef __attribute__((ext_vector_type(8))) int intx8;
typedef __attribute__((ext_vector_type(4))) float floatx4;
typedef __attribute__((ext_vector_type(4))) short short4v;
typedef __attribute__((ext_vector_type(4))) unsigned short ushort4v;

__device__ __forceinline__ unsigned short f32_to_bf16_bits(float f) {
  unsigned int u = __float_as_uint(f);
  u += 0x7FFFu + ((u >> 16) & 1u);  // RNE
  return (unsigned short)(u >> 16);
}
__device__ __forceinline__ float bf16_bits_to_f32(unsigned short s) {
  return __uint_as_float(((unsigned int)s) << 16);
}

// OCP e4m3fn quantization, manual RNE (unbiased). Input in [0, 448].
__device__ __forceinline__ unsigned char f32_to_e4m3(float v) {
  if (!(v > 0.f)) return 0;
  unsigned u = __float_as_uint(v);
  int e = (int)((u >> 23) & 0xFF) - 127;
  if (e >= -6) {                      // normal e4m3
    unsigned m = u & 0x7FFFFF;
    unsigned keep = m >> 20;
    unsigned rem = m & 0xFFFFF;
    keep += (rem > 0x80000u) || (rem == 0x80000u && (keep & 1u));
    if (keep == 8u) { keep = 0u; e += 1; }
    return (unsigned char)(((e + 7) << 3) | keep);
  }
  if (e < -10) return 0;
  float scaled = v * 512.f;           // 2^9
  int m4 = (int)rintf(scaled);        // RNE
  if (m4 >= 8) return 0x08;
  return (unsigned char)m4;
}

__device__ __forceinline__ void gld_lds16(const void* g, void* l) {
  __builtin_amdgcn_global_load_lds(
      (const __attribute__((address_space(1))) void*)g,
      (__attribute__((address_space(3))) void*)l, 16, 0, 0);
}

// --- fused prep: blocks [0,4096): adj fp32 -> fp8(x2^13) a + at;
//                 blocks [4096,4608): RMT[b*32+f][j] = bf16(rm[b,j,f]) + dvec=0
__global__ __launch_bounds__(256) void k_prep(const float* __restrict__ adj,
                                              unsigned char* __restrict__ a,
                                              unsigned char* __restrict__ at,
                                              const float* __restrict__ rm,
                                              unsigned short* __restrict__ rmt,
                                              float* __restrict__ dvec) {
  __shared__ __align__(16) float tile[64][65];
  const int bx = blockIdx.x;
  const int t = threadIdx.x;
  if (bx < 4096) {
    const int row0 = (bx >> 6) * 64, col0 = (bx & 63) * 64;
    const int c4 = (t & 15) * 4;
    const int r = t >> 4;
    for (int rr = 0; rr < 64; rr += 16) {
      float4 v = *(const float4*)(adj + (size_t)(row0 + r + rr) * 4096 + col0 + c4);
      tile[r + rr][c4 + 0] = v.x;
      tile[r + rr][c4 + 1] = v.y;
      tile[r + rr][c4 + 2] = v.z;
      tile[r + rr][c4 + 3] = v.w;
      unsigned char q[4];
      q[0] = f32_to_e4m3(v.x * 8192.f);
      q[1] = f32_to_e4m3(v.y * 8192.f);
      q[2] = f32_to_e4m3(v.z * 8192.f);
      q[3] = f32_to_e4m3(v.w * 8192.f);
      *(unsigned int*)(a + (size_t)(row0 + r + rr) * 4096 + col0 + c4) =
          *(const unsigned int*)q;
    }
    __syncthreads();
    for (int rr = 0; rr < 64; rr += 16) {
      const int orow = r + rr;
      unsigned char q[4];
      q[0] = f32_to_e4m3(tile[c4 + 0][orow] * 8192.f);
      q[1] = f32_to_e4m3(tile[c4 + 1][orow] * 8192.f);
      q[2] = f32_to_e4m3(tile[c4 + 2][orow] * 8192.f);
      q[3] = f32_to_e4m3(tile[c4 + 3][orow] * 8192.f);
      *(unsigned int*)(at + (size_t)(col0 + orow) * 4096 + row0 + c4) =
          *(const unsigned int*)q;
    }
  } else {
    unsigned short(*tile2)[33] = (unsigned short(*)[33])tile;
    const int idx = bx - 4096;           // [0,512)
    const int b = idx & 7;
    const int j0 = (idx >> 3) * 64;
    const int z = (idx >> 3) * 256 + t;  // dvec zeroing (first 16 j-tiles)
    if (b == 0 && z < 4096) dvec[z] = 0.f;
    #pragma unroll
    for (int p = 0; p < 2; ++p) {
      const int j = (t >> 3) + p * 32;
      const int f4 = (t & 7) * 4;
      float4 v = *(const float4*)(rm + ((size_t)b * 4096 + j0 + j) * 32 + f4);
      tile2[j][f4 + 0] = f32_to_bf16_bits(v.x);
      tile2[j][f4 + 1] = f32_to_bf16_bits(v.y);
      tile2[j][f4 + 2] = f32_to_bf16_bits(v.z);
      tile2[j][f4 + 3] = f32_to_bf16_bits(v.w);
    }
    __syncthreads();
    const int f = t >> 3, j8 = (t & 7) * 8;
    unsigned short tmp[8];
    #pragma unroll
    for (int k = 0; k < 8; ++k) tmp[k] = tile2[j8 + k][f];
    *(int4*)(rmt + ((size_t)b * 32 + f) * 4096 + j0 + j8) = *(const int4*)tmp;
  }
}

// --- d[i] = sum_j A2[i,j]*A2[j,i] ------------------------------------------
__global__ __launch_bounds__(256) void k_diag(const unsigned short* __restrict__ M2,
                                              float* __restrict__ d) {
  constexpr int P = 72;
  __shared__ __align__(16) unsigned short t1[64 * P];
  __shared__ __align__(16) unsigned short t2[64 * P];
  __shared__ float red[256];
  const int I = blockIdx.x >> 6, J = blockIdx.x & 63;
  const int t = threadIdx.x;
  for (int c = t; c < 512; c += 256) {
    const int row = c >> 3, col = (c & 7) * 8;
    *(int4*)(t1 + row * P + col) =
        *(const int4*)(M2 + (size_t)(I * 64 + row) * 4096 + J * 64 + col);
    *(int4*)(t2 + row * P + col) =
        *(const int4*)(M2 + (size_t)(J * 64 + row) * 4096 + I * 64 + col);
  }
  __syncthreads();
  const int i = t & 63, q = t >> 6;
  float s = 0.f;
  #pragma unroll
  for (int jj = 0; jj < 16; ++jj) {
    const int j = q * 16 + jj;
    s += bf16_bits_to_f32(t1[i * P + j]) * bf16_bits_to_f32(t2[j * P + i]);
  }
  red[t] = s;
  __syncthreads();
  if (t < 64) {
    const float tot = red[t] + red[t + 64] + red[t + 128] + red[t + 192];
    atomicAdd(&d[I * 64 + t], tot);
  }
}

// --- big GEMM (MX-fp8): C = A @ BT^T, 128x128 tile, BK=128 (FROZEN) ---------
__global__ __launch_bounds__(256) void k_gemm_big_fp8(const unsigned char* __restrict__ A,
                                                      const unsigned char* __restrict__ BT,
                                                      unsigned short* __restrict__ C,
                                                      int M, int N, int K) {
  __shared__ __align__(16) unsigned char smA[128 * 128];
  __shared__ __align__(16) unsigned char smB[128 * 128];
  const int tid = threadIdx.x;
  const int wave = tid >> 6, lane = tid & 63;
  const int quad = lane >> 4, l16 = lane & 15;
  const int wm = (wave & 1) * 64, wn = (wave >> 1) * 64;
  const int m0 = blockIdx.x * 128, n0 = blockIdx.y * 128;
  const int srow = lane >> 3;                 // 0..7
  const int gcol = ((lane & 7) ^ srow) * 16;  // swizzled byte col

  floatx4 acc[4][4];
  #pragma unroll
  for (int i = 0; i < 4; ++i)
    #pragma unroll
    for (int j = 0; j < 4; ++j) acc[i][j] = floatx4{0.f, 0.f, 0.f, 0.f};

  for (int k0 = 0; k0 < K; k0 += 128) {
    #pragma unroll
    for (int c = 0; c < 4; ++c) {
      const int ch = wave * 4 + c;  // 16 chunks of 1KB each per operand
      const int row = ch * 8 + srow;
      gld_lds16(A + (size_t)(m0 + row) * K + k0 + gcol, smA + ch * 1024);
      gld_lds16(BT + (size_t)(n0 + row) * K + k0 + gcol, smB + ch * 1024);
    }
    __syncthreads();
    intx8 af[4], bfr[4];
    #pragma unroll
    for (int i = 0; i < 4; ++i) {
      const int row = wm + i * 16 + l16;
      const int x = l16 & 7;
      const int4 lo = *(const int4*)(smA + row * 128 + (((2 * quad) ^ x) * 16));
      const int4 hi = *(const int4*)(smA + row * 128 + (((2 * quad + 1) ^ x) * 16));
      af[i] = intx8{lo.x, lo.y, lo.z, lo.w, hi.x, hi.y, hi.z, hi.w};
    }
    #pragma unroll
    for (int j = 0; j < 4; ++j) {
      const int row = wn + j * 16 + l16;
      const int x = l16 & 7;
      const int4 lo = *(const int4*)(smB + row * 128 + (((2 * quad) ^ x) * 16));
      const int4 hi = *(const int4*)(smB + row * 128 + (((2 * quad + 1) ^ x) * 16));
      bfr[j] = intx8{lo.x, lo.y, lo.z, lo.w, hi.x, hi.y, hi.z, hi.w};
    }
    #pragma unroll
    for (int i = 0; i < 4; ++i)
      #pragma unroll
      for (int j = 0; j < 4; ++j)
        acc[i][j] = __builtin_amdgcn_mfma_scale_f32_16x16x128_f8f6f4(
            af[i], bfr[j], acc[i][j], 0, 0,      // cbsz=fp8, blgp=fp8
            0, 0x7F7F7F7F, 0, 0x7F7F7F7F);       // scales = 2^0
    __syncthreads();
  }
  const float unscale = 1.4901161193847656e-8f;  // 2^-26
  #pragma unroll
  for (int i = 0; i < 4; ++i) {
    #pragma unroll
    for (int j = 0; j < 4; ++j) {
      const int rowb = m0 + wm + i * 16 + quad * 4;
      const int col = n0 + wn + j * 16 + l16;
      #pragma unroll
      for (int r = 0; r < 4; ++r)
        C[(size_t)(rowb + r) * N + col] = f32_to_bf16_bits(acc[i][j][r] * unscale);
    }
  }
}

// --- skinny split-K GEMM: BM=64, BN=128, BK=64, dbuf LDS --------------------
// C[m][n] = sum_k A[m][k]*BT[n][k]; bf16 partials P[kt*1M + m*ldPn + n].
// grid (M/64, N/128, K/KC).
template <int KC>
__global__ __launch_bounds__(256) void k_gemm_skinny(const unsigned short* __restrict__ A,
                                                     const unsigned short* __restrict__ BT,
                                                     unsigned short* __restrict__ P,
                                                     int K, int ldPn) {
  constexpr int NITER = KC / 64;
  __shared__ __align__(16) unsigned short smA[2][64 * 64];
  __shared__ __align__(16) unsigned short smB[2][128 * 64];
  const int tid = threadIdx.x;
  const int wave = tid >> 6, lane = tid & 63;
  const int quad = lane >> 4, l16 = lane & 15;
  const int m0 = blockIdx.x * 64;
  const int n0 = blockIdx.y * 128;
  const int kt = blockIdx.z;
  const int wm = (wave & 1) * 32, wn = (wave >> 1) * 64;
  const int srow = lane >> 3;
  const int gcol = ((lane & 7) ^ srow) * 8;
  const int kbeg = kt * KC;

  floatx4 acc[2][4];
  #pragma unroll
  for (int i = 0; i < 2; ++i)
    #pragma unroll
    for (int j = 0; j < 4; ++j) acc[i][j] = floatx4{0.f, 0.f, 0.f, 0.f};

  auto stage = [&](int buf, int k0) {  // 24 chunks of 1KB (A:0-7, B:8-23)
    #pragma unroll
    for (int u = 0; u < 6; ++u) {
      const int ch = wave * 6 + u;
      if (ch < 8) {
        const int row = ch * 8 + srow;
        gld_lds16(A + (size_t)(m0 + row) * K + k0 + gcol, &smA[buf][ch * 512]);
      } else {
        const int c2 = ch - 8;
        const int row = c2 * 8 + srow;
        gld_lds16(BT + (size_t)(n0 + row) * K + k0 + gcol, &smB[buf][c2 * 512]);
      }
    }
  };

  stage(0, kbeg);
  for (int it = 0; it < NITER; ++it) {
    const int buf = it & 1;
    __syncthreads();  // buf staged (drains vmcnt)
    if (it + 1 < NITER) stage(buf ^ 1, kbeg + (it + 1) * 64);  // prefetch
    #pragma unroll
    for (int kk = 0; kk < 64; kk += 32) {
      const int g8 = quad + (kk >> 3);
      bf16x8 af[2], bfr[4];
      #pragma unroll
      for (int i = 0; i < 2; ++i) {
        const int row = wm + i * 16 + l16;
        af[i] = *(const bf16x8*)(&smA[buf][row * 64 + ((g8 ^ (row & 7)) * 8)]);
      }
      #pragma unroll
      for (int j = 0; j < 4; ++j) {
        const int row = wn + j * 16 + l16;
        bfr[j] = *(const bf16x8*)(&smB[buf][row * 64 + ((g8 ^ (row & 7)) * 8)]);
      }
      #pragma unroll
      for (int i = 0; i < 2; ++i)
        #pragma unroll
        for (int j = 0; j < 4; ++j)
          acc[i][j] = __builtin_amdgcn_mfma_f32_16x16x32_bf16(af[i], bfr[j],
                                                              acc[i][j], 0, 0, 0);
    }
  }
  #pragma unroll
  for (int i = 0; i < 2; ++i) {
    #pragma unroll
    for (int j = 0; j < 4; ++j) {
      const int rowl = wm + i * 16 + quad * 4;
      const int col = n0 + wn + j * 16 + l16;
      #pragma unroll
      for (int r = 0; r < 4; ++r)
        P[(size_t)kt * 1048576 + (size_t)(m0 + rowl + r) * ldPn + col] =
            f32_to_bf16_bits(acc[i][j][r]);
    }
  }
}

// --- flat reduce: T1T[e] = bf16(sum_kt P[kt*1M + e]), vectorized x4 ---------
template <int NKT>
__global__ __launch_bounds__(256) void k_reduce_flat(const unsigned short* __restrict__ P,
                                                     unsigned short* __restrict__ O) {
  const size_t base = ((size_t)blockIdx.x * 256 + threadIdx.x) * 4;
  float s0 = 0.f, s1 = 0.f, s2 = 0.f, s3 = 0.f;
  #pragma unroll
  for (int kt = 0; kt < NKT; ++kt) {
    ushort4v v = *(const ushort4v*)(P + (size_t)kt * 1048576 + base);
    s0 += bf16_bits_to_f32(v.x);
    s1 += bf16_bits_to_f32(v.y);
    s2 += bf16_bits_to_f32(v.z);
    s3 += bf16_bits_to_f32(v.w);
  }
  ushort4v o;
  o.x = f32_to_bf16_bits(s0);
  o.y = f32_to_bf16_bits(s1);
  o.z = f32_to_bf16_bits(s2);
  o.w = f32_to_bf16_bits(s3);
  *(ushort4v*)(O + base) = o;
}

// --- reduce partials + fused epilogue: out = sum P - d[row]*rm, vec x4 ------
template <int NKT>
__global__ __launch_bounds__(256) void k_reduce_out(const unsigned short* __restrict__ P,
                                                    const float* __restrict__ dvec,
                                                    const float* __restrict__ rm,
                                                    float* __restrict__ out) {
  const size_t base = ((size_t)blockIdx.x * 256 + threadIdx.x) * 4;  // row*256+col
  const int row = (int)(base >> 8);
  const int col = (int)(base & 255);
  float s0 = 0.f, s1 = 0.f, s2 = 0.f, s3 = 0.f;
  #pragma unroll
  for (int kt = 0; kt < NKT; ++kt) {
    ushort4v v = *(const ushort4v*)(P + (size_t)kt * 1048576 + base);
    s0 += bf16_bits_to_f32(v.x);
    s1 += bf16_bits_to_f32(v.y);
    s2 += bf16_bits_to_f32(v.z);
    s3 += bf16_bits_to_f32(v.w);
  }
  const int b = col >> 5, f = col & 31;  // 4 consecutive f within one b
  const size_t o = ((size_t)b * 4096 + row) * 32 + f;
  const float dv = dvec[row];
  const float4 rv = *(const float4*)(rm + o);
  float4 ov;
  ov.x = s0 - dv * rv.x;
  ov.y = s1 - dv * rv.y;
  ov.z = s2 - dv * rv.z;
  ov.w = s3 - dv * rv.w;
  *(float4*)(out + o) = ov;
}

extern "C" void kernel_launch(void* const* d_in, const int* in_sizes, int n_in,
                              void* d_out, int out_size, void* d_ws, size_t ws_size,
                              hipStream_t stream) {
  const float* rm = (const float*)d_in[0];   // (8, 4096, 32) fp32
  const float* adj = (const float*)d_in[1];  // (4096, 4096) fp32
  float* out = (float*)d_out;
  char* ws = (char*)d_ws;

  unsigned char* A8    = (unsigned char*)(ws);              // 16 MiB (dead after big GEMM)
  unsigned char* A8T   = (unsigned char*)(ws + 16777216);   // 16 MiB (dead after big GEMM)
  unsigned short* A2bf = (unsigned short*)(ws + 67108864);  // 32 MiB
  unsigned short* RMT  = (unsigned short*)(ws + 100663296); // 2 MiB
  unsigned short* T1T  = (unsigned short*)(ws + 102760448); // 2 MiB
  float* dvec          = (float*)(ws + 104857600);          // 16 KiB
  unsigned short* Pp   = (unsigned short*)(ws);             // 32 MiB, reuses A8/A8T

  // prep: adj->fp8 (a, at) + RMT + dvec=0, one dispatch
  k_prep<<<4608, 256, 0, stream>>>(adj, A8, A8T, rm, RMT, dvec);

  // A2 = adj @ adj  (MX-fp8, constant scale)
  k_gemm_big_fp8<<<dim3(32, 32), 256, 0, stream>>>(A8, A8T, A2bf, 4096, 4096, 4096);

  // d[i] = sum_j A2[i,j] * A2[j,i]   (A8/A8T now dead; Pp reuses the space)
  k_diag<<<4096, 256, 0, stream>>>(A2bf, dvec);

  // T1T = gemm(A=RMT, BT=A2): direct transposed layout, 16-way split-K
  k_gemm_skinny<256><<<dim3(4, 32, 16), 256, 0, stream>>>(RMT, A2bf, Pp, 4096, 4096);
  k_reduce_flat<16><<<1024, 256, 0, stream>>>(Pp, T1T);

  // T2 = gemm(A=A2, BT=T1T) -> fused out = T2 - d*rm
  k_gemm_skinny<256><<<dim3(64, 2, 16), 256, 0, stream>>>(A2bf, T1T, Pp, 4096, 256);
  k_reduce_out<16><<<1024, 256, 0, stream>>>(Pp, dvec, rm, out);
}

// Round 9
// 230.832 us; speedup vs baseline: 1.1389x; 1.1389x over previous
//
#include <hip/hip_runtime.h>

// ---------------------------------------------------------------------------
// SGC: out[b,i,f] = sum_{j!=i} (adj^4)[i,j] * rm[b,j,f]
//   A2   = adj @ adj          (MX-fp8 e4m3 MFMA K=128, 4096^3, const scale)
//   T1   = A2 @ RM            (split-K KC=512, bf16 partials; FUSED with diag)
//   out  = A2 @ T1 - d*rm     (split-K, bf16 partials, fused vec reduce)
//   d[i] = sum_j A2[i,j]*A2[j,i]  (triangular tile-pairs, fused into skinny1)
// Lessons encoded:
//  - A2 must be the M-side operand of the skinnies (read once per N-tile);
//    swapping it to B-side quadrupled its HBM traffic and regressed (r8).
//  - KC=512/8-way split beats 16-way (partial traffic > TLP gain, r8).
//  - LDS-free fragment-direct skinny regressed 2x (r6): keep LDS staging.
//  - fp8 LDS conflicts (8.39e6) are structural, not the critical pipe (r5).
//  - Same-address split-K atomics regressed (r3): explicit partials.
// ---------------------------------------------------------------------------

typedef __attribute__((ext_vector_type(8))) __bf16 bf16x8;
typedef __attribute__((ext_vector_type(8))) int intx8;
typedef __attribute__((ext_vector_type(4))) float floatx4;
typedef __attribute__((ext_vector_type(4))) short short4v;
typedef __attribute__((ext_vector_type(4))) unsigned short ushort4v;

__device__ __forceinline__ unsigned short f32_to_bf16_bits(float f) {
  unsigned int u = __float_as_uint(f);
  u += 0x7FFFu + ((u >> 16) & 1u);  // RNE
  return (unsigned short)(u >> 16);
}
__device__ __forceinline__ float bf16_bits_to_f32(unsigned short s) {
  return __uint_as_float(((unsigned int)s) << 16);
}

// OCP e4m3fn quantization, manual RNE (unbiased). Input in [0, 448].
__device__ __forceinline__ unsigned char f32_to_e4m3(float v) {
  if (!(v > 0.f)) return 0;
  unsigned u = __float_as_uint(v);
  int e = (int)((u >> 23) & 0xFF) - 127;
  if (e >= -6) {                      // normal e4m3
    unsigned m = u & 0x7FFFFF;
    unsigned keep = m >> 20;
    unsigned rem = m & 0xFFFFF;
    keep += (rem > 0x80000u) || (rem == 0x80000u && (keep & 1u));
    if (keep == 8u) { keep = 0u; e += 1; }
    return (unsigned char)(((e + 7) << 3) | keep);
  }
  if (e < -10) return 0;
  float scaled = v * 512.f;           // 2^9
  int m4 = (int)rintf(scaled);        // RNE
  if (m4 >= 8) return 0x08;
  return (unsigned char)m4;
}

__device__ __forceinline__ void gld_lds16(const void* g, void* l) {
  __builtin_amdgcn_global_load_lds(
      (const __attribute__((address_space(1))) void*)g,
      (__attribute__((address_space(3))) void*)l, 16, 0, 0);
}

// --- fused prep: blocks [0,4096): adj fp32 -> fp8(x2^13) a + at;
//                 blocks [4096,4608): RMT[b*32+f][j] = bf16(rm[b,j,f]) + dvec=0
__global__ __launch_bounds__(256) void k_prep(const float* __restrict__ adj,
                                              unsigned char* __restrict__ a,
                                              unsigned char* __restrict__ at,
                                              const float* __restrict__ rm,
                                              unsigned short* __restrict__ rmt,
                                              float* __restrict__ dvec) {
  __shared__ __align__(16) float tile[64][65];
  const int bx = blockIdx.x;
  const int t = threadIdx.x;
  if (bx < 4096) {
    const int row0 = (bx >> 6) * 64, col0 = (bx & 63) * 64;
    const int c4 = (t & 15) * 4;
    const int r = t >> 4;
    for (int rr = 0; rr < 64; rr += 16) {
      float4 v = *(const float4*)(adj + (size_t)(row0 + r + rr) * 4096 + col0 + c4);
      tile[r + rr][c4 + 0] = v.x;
      tile[r + rr][c4 + 1] = v.y;
      tile[r + rr][c4 + 2] = v.z;
      tile[r + rr][c4 + 3] = v.w;
      unsigned char q[4];
      q[0] = f32_to_e4m3(v.x * 8192.f);
      q[1] = f32_to_e4m3(v.y * 8192.f);
      q[2] = f32_to_e4m3(v.z * 8192.f);
      q[3] = f32_to_e4m3(v.w * 8192.f);
      *(unsigned int*)(a + (size_t)(row0 + r + rr) * 4096 + col0 + c4) =
          *(const unsigned int*)q;
    }
    __syncthreads();
    for (int rr = 0; rr < 64; rr += 16) {
      const int orow = r + rr;
      unsigned char q[4];
      q[0] = f32_to_e4m3(tile[c4 + 0][orow] * 8192.f);
      q[1] = f32_to_e4m3(tile[c4 + 1][orow] * 8192.f);
      q[2] = f32_to_e4m3(tile[c4 + 2][orow] * 8192.f);
      q[3] = f32_to_e4m3(tile[c4 + 3][orow] * 8192.f);
      *(unsigned int*)(at + (size_t)(col0 + orow) * 4096 + row0 + c4) =
          *(const unsigned int*)q;
    }
  } else {
    unsigned short(*tile2)[33] = (unsigned short(*)[33])tile;
    const int idx = bx - 4096;           // [0,512)
    const int b = idx & 7;
    const int j0 = (idx >> 3) * 64;
    const int z = (idx >> 3) * 256 + t;  // dvec zeroing (first 16 j-tiles)
    if (b == 0 && z < 4096) dvec[z] = 0.f;
    #pragma unroll
    for (int p = 0; p < 2; ++p) {
      const int j = (t >> 3) + p * 32;
      const int f4 = (t & 7) * 4;
      float4 v = *(const float4*)(rm + ((size_t)b * 4096 + j0 + j) * 32 + f4);
      tile2[j][f4 + 0] = f32_to_bf16_bits(v.x);
      tile2[j][f4 + 1] = f32_to_bf16_bits(v.y);
      tile2[j][f4 + 2] = f32_to_bf16_bits(v.z);
      tile2[j][f4 + 3] = f32_to_bf16_bits(v.w);
    }
    __syncthreads();
    const int f = t >> 3, j8 = (t & 7) * 8;
    unsigned short tmp[8];
    #pragma unroll
    for (int k = 0; k < 8; ++k) tmp[k] = tile2[j8 + k][f];
    *(int4*)(rmt + ((size_t)b * 32 + f) * 4096 + j0 + j8) = *(const int4*)tmp;
  }
}

// --- big GEMM (MX-fp8): C = A @ BT^T, 128x128 tile, BK=128 (FROZEN) ---------
__global__ __launch_bounds__(256) void k_gemm_big_fp8(const unsigned char* __restrict__ A,
                                                      const unsigned char* __restrict__ BT,
                                                      unsigned short* __restrict__ C,
                                                      int M, int N, int K) {
  __shared__ __align__(16) unsigned char smA[128 * 128];
  __shared__ __align__(16) unsigned char smB[128 * 128];
  const int tid = threadIdx.x;
  const int wave = tid >> 6, lane = tid & 63;
  const int quad = lane >> 4, l16 = lane & 15;
  const int wm = (wave & 1) * 64, wn = (wave >> 1) * 64;
  const int m0 = blockIdx.x * 128, n0 = blockIdx.y * 128;
  const int srow = lane >> 3;                 // 0..7
  const int gcol = ((lane & 7) ^ srow) * 16;  // swizzled byte col

  floatx4 acc[4][4];
  #pragma unroll
  for (int i = 0; i < 4; ++i)
    #pragma unroll
    for (int j = 0; j < 4; ++j) acc[i][j] = floatx4{0.f, 0.f, 0.f, 0.f};

  for (int k0 = 0; k0 < K; k0 += 128) {
    #pragma unroll
    for (int c = 0; c < 4; ++c) {
      const int ch = wave * 4 + c;  // 16 chunks of 1KB each per operand
      const int row = ch * 8 + srow;
      gld_lds16(A + (size_t)(m0 + row) * K + k0 + gcol, smA + ch * 1024);
      gld_lds16(BT + (size_t)(n0 + row) * K + k0 + gcol, smB + ch * 1024);
    }
    __syncthreads();
    intx8 af[4], bfr[4];
    #pragma unroll
    for (int i = 0; i < 4; ++i) {
      const int row = wm + i * 16 + l16;
      const int x = l16 & 7;
      const int4 lo = *(const int4*)(smA + row * 128 + (((2 * quad) ^ x) * 16));
      const int4 hi = *(const int4*)(smA + row * 128 + (((2 * quad + 1) ^ x) * 16));
      af[i] = intx8{lo.x, lo.y, lo.z, lo.w, hi.x, hi.y, hi.z, hi.w};
    }
    #pragma unroll
    for (int j = 0; j < 4; ++j) {
      const int row = wn + j * 16 + l16;
      const int x = l16 & 7;
      const int4 lo = *(const int4*)(smB + row * 128 + (((2 * quad) ^ x) * 16));
      const int4 hi = *(const int4*)(smB + row * 128 + (((2 * quad + 1) ^ x) * 16));
      bfr[j] = intx8{lo.x, lo.y, lo.z, lo.w, hi.x, hi.y, hi.z, hi.w};
    }
    #pragma unroll
    for (int i = 0; i < 4; ++i)
      #pragma unroll
      for (int j = 0; j < 4; ++j)
        acc[i][j] = __builtin_amdgcn_mfma_scale_f32_16x16x128_f8f6f4(
            af[i], bfr[j], acc[i][j], 0, 0,      // cbsz=fp8, blgp=fp8
            0, 0x7F7F7F7F, 0, 0x7F7F7F7F);       // scales = 2^0
    __syncthreads();
  }
  const float unscale = 1.4901161193847656e-8f;  // 2^-26
  #pragma unroll
  for (int i = 0; i < 4; ++i) {
    #pragma unroll
    for (int j = 0; j < 4; ++j) {
      const int rowb = m0 + wm + i * 16 + quad * 4;
      const int col = n0 + wn + j * 16 + l16;
      #pragma unroll
      for (int r = 0; r < 4; ++r)
        C[(size_t)(rowb + r) * N + col] = f32_to_bf16_bits(acc[i][j][r] * unscale);
    }
  }
}

// --- FUSED: diag (triangular, blocks [0,2112)) + skinny1 (blocks [2112,3136))
// diag: block (I, Jo): J=(I+Jo)&63; loads A2 tile-pair, contributes to both
//       d[I-tile] and d[J-tile]. Jo==0: diagonal tile; Jo==32 only for I<32.
// skinny1: T1 = A2 @ RMT^T; BM=64, BN=128, KC=512, dbuf LDS, bf16 partials
//          P[kt][4096][256].
__global__ __launch_bounds__(256) void k_diag_skinny1(
    const unsigned short* __restrict__ A2,
    const unsigned short* __restrict__ RMT,
    unsigned short* __restrict__ P,
    float* __restrict__ d) {
  __shared__ __align__(16) char smem[49152];
  const int t = threadIdx.x;
  const int bx = blockIdx.x;

  if (bx < 2112) {
    // ---------------- diag part ----------------
    constexpr int PP = 72;
    unsigned short* t1 = (unsigned short*)smem;
    unsigned short* t2 = t1 + 64 * PP;
    float* red = (float*)(smem + 2 * 64 * PP * 2);  // offset 18432
    const int I = bx & 63;
    const int Jo = bx >> 6;  // 0..32
    if (Jo == 32 && I >= 32) return;
    const int J = (I + Jo) & 63;
    for (int c = t; c < 512; c += 256) {
      const int row = c >> 3, col = (c & 7) * 8;
      *(int4*)(t1 + row * PP + col) =
          *(const int4*)(A2 + (size_t)(I * 64 + row) * 4096 + J * 64 + col);
      if (Jo)
        *(int4*)(t2 + row * PP + col) =
            *(const int4*)(A2 + (size_t)(J * 64 + row) * 4096 + I * 64 + col);
    }
    __syncthreads();
    const unsigned short* tt2 = Jo ? t2 : t1;
    const int i = t & 63, q = t >> 6;
    float s1 = 0.f, s2 = 0.f;
    #pragma unroll
    for (int jj = 0; jj < 16; ++jj) {
      const int j = q * 16 + jj;
      s1 += bf16_bits_to_f32(t1[i * PP + j]) * bf16_bits_to_f32(tt2[j * PP + i]);
      if (Jo)
        s2 += bf16_bits_to_f32(t2[i * PP + j]) * bf16_bits_to_f32(t1[j * PP + i]);
    }
    red[t] = s1;
    __syncthreads();
    if (t < 64)
      atomicAdd(&d[I * 64 + t], red[t] + red[t + 64] + red[t + 128] + red[t + 192]);
    if (Jo) {
      __syncthreads();
      red[t] = s2;
      __syncthreads();
      if (t < 64)
        atomicAdd(&d[J * 64 + t], red[t] + red[t + 64] + red[t + 128] + red[t + 192]);
    }
    return;
  }

  // ---------------- skinny1 part ----------------
  constexpr int KC = 512;
  constexpr int NITER = KC / 64;
  const int K = 4096;
  unsigned short* smA = (unsigned short*)smem;            // [2][64*64]
  unsigned short* smB = (unsigned short*)(smem + 16384);  // [2][128*64]
  const int bx2 = bx - 2112;
  const int wave = t >> 6, lane = t & 63;
  const int quad = lane >> 4, l16 = lane & 15;
  const int m0 = (bx2 & 63) * 64;
  const int n0 = ((bx2 >> 6) & 1) * 128;
  const int kt = bx2 >> 7;
  const int wm = (wave & 1) * 32, wn = (wave >> 1) * 64;
  const int srow = lane >> 3;
  const int gcol = ((lane & 7) ^ srow) * 8;
  const int kbeg = kt * KC;

  floatx4 acc[2][4];
  #pragma unroll
  for (int i = 0; i < 2; ++i)
    #pragma unroll
    for (int j = 0; j < 4; ++j) acc[i][j] = floatx4{0.f, 0.f, 0.f, 0.f};

  auto stage = [&](int buf, int k0) {  // 24 chunks of 1KB (A:0-7, B:8-23)
    #pragma unroll
    for (int u = 0; u < 6; ++u) {
      const int ch = wave * 6 + u;
      if (ch < 8) {
        const int row = ch * 8 + srow;
        gld_lds16(A2 + (size_t)(m0 + row) * K + k0 + gcol,
                  smA + buf * 4096 + ch * 512);
      } else {
        const int c2 = ch - 8;
        const int row = c2 * 8 + srow;
        gld_lds16(RMT + (size_t)(n0 + row) * K + k0 + gcol,
                  smB + buf * 8192 + c2 * 512);
      }
    }
  };

  stage(0, kbeg);
  for (int it = 0; it < NITER; ++it) {
    const int buf = it & 1;
    __syncthreads();  // buf staged (drains vmcnt)
    if (it + 1 < NITER) stage(buf ^ 1, kbeg + (it + 1) * 64);  // prefetch
    #pragma unroll
    for (int kk = 0; kk < 64; kk += 32) {
      const int g8 = quad + (kk >> 3);
      bf16x8 af[2], bfr[4];
      #pragma unroll
      for (int i = 0; i < 2; ++i) {
        const int row = wm + i * 16 + l16;
        af[i] = *(const bf16x8*)(smA + buf * 4096 + row * 64 + ((g8 ^ (row & 7)) * 8));
      }
      #pragma unroll
      for (int j = 0; j < 4; ++j) {
        const int row = wn + j * 16 + l16;
        bfr[j] = *(const bf16x8*)(smB + buf * 8192 + row * 64 + ((g8 ^ (row & 7)) * 8));
      }
      #pragma unroll
      for (int i = 0; i < 2; ++i)
        #pragma unroll
        for (int j = 0; j < 4; ++j)
          acc[i][j] = __builtin_amdgcn_mfma_f32_16x16x32_bf16(af[i], bfr[j],
                                                              acc[i][j], 0, 0, 0);
    }
  }
  #pragma unroll
  for (int i = 0; i < 2; ++i) {
    #pragma unroll
    for (int j = 0; j < 4; ++j) {
      const int rowl = wm + i * 16 + quad * 4;
      const int col = n0 + wn + j * 16 + l16;
      #pragma unroll
      for (int r = 0; r < 4; ++r)
        P[(size_t)kt * 1048576 + (size_t)(m0 + rowl + r) * 256 + col] =
            f32_to_bf16_bits(acc[i][j][r]);
    }
  }
}

// --- skinny2: same GEMM structure, standalone (A=A2, BT=T1T) ----------------
template <int KC>
__global__ __launch_bounds__(256) void k_gemm_skinny(const unsigned short* __restrict__ A,
                                                     const unsigned short* __restrict__ BT,
                                                     unsigned short* __restrict__ P, int K) {
  constexpr int NITER = KC / 64;
  __shared__ __align__(16) unsigned short smA[2][64 * 64];
  __shared__ __align__(16) unsigned short smB[2][128 * 64];
  const int tid = threadIdx.x;
  const int wave = tid >> 6, lane = tid & 63;
  const int quad = lane >> 4, l16 = lane & 15;
  const int m0 = blockIdx.x * 64;
  const int n0 = blockIdx.y * 128;
  const int kt = blockIdx.z;
  const int wm = (wave & 1) * 32, wn = (wave >> 1) * 64;
  const int srow = lane >> 3;
  const int gcol = ((lane & 7) ^ srow) * 8;
  const int kbeg = kt * KC;

  floatx4 acc[2][4];
  #pragma unroll
  for (int i = 0; i < 2; ++i)
    #pragma unroll
    for (int j = 0; j < 4; ++j) acc[i][j] = floatx4{0.f, 0.f, 0.f, 0.f};

  auto stage = [&](int buf, int k0) {
    #pragma unroll
    for (int u = 0; u < 6; ++u) {
      const int ch = wave * 6 + u;
      if (ch < 8) {
        const int row = ch * 8 + srow;
        gld_lds16(A + (size_t)(m0 + row) * K + k0 + gcol, &smA[buf][ch * 512]);
      } else {
        const int c2 = ch - 8;
        const int row = c2 * 8 + srow;
        gld_lds16(BT + (size_t)(n0 + row) * K + k0 + gcol, &smB[buf][c2 * 512]);
      }
    }
  };

  stage(0, kbeg);
  for (int it = 0; it < NITER; ++it) {
    const int buf = it & 1;
    __syncthreads();
    if (it + 1 < NITER) stage(buf ^ 1, kbeg + (it + 1) * 64);
    #pragma unroll
    for (int kk = 0; kk < 64; kk += 32) {
      const int g8 = quad + (kk >> 3);
      bf16x8 af[2], bfr[4];
      #pragma unroll
      for (int i = 0; i < 2; ++i) {
        const int row = wm + i * 16 + l16;
        af[i] = *(const bf16x8*)(&smA[buf][row * 64 + ((g8 ^ (row & 7)) * 8)]);
      }
      #pragma unroll
      for (int j = 0; j < 4; ++j) {
        const int row = wn + j * 16 + l16;
        bfr[j] = *(const bf16x8*)(&smB[buf][row * 64 + ((g8 ^ (row & 7)) * 8)]);
      }
      #pragma unroll
      for (int i = 0; i < 2; ++i)
        #pragma unroll
        for (int j = 0; j < 4; ++j)
          acc[i][j] = __builtin_amdgcn_mfma_f32_16x16x32_bf16(af[i], bfr[j],
                                                              acc[i][j], 0, 0, 0);
    }
  }
  #pragma unroll
  for (int i = 0; i < 2; ++i) {
    #pragma unroll
    for (int j = 0; j < 4; ++j) {
      const int rowl = wm + i * 16 + quad * 4;
      const int col = n0 + wn + j * 16 + l16;
      #pragma unroll
      for (int r = 0; r < 4; ++r)
        P[((size_t)kt * 4096 + m0 + rowl + r) * 256 + col] =
            f32_to_bf16_bits(acc[i][j][r]);
    }
  }
}

// --- reduce bf16 partials -> T1T bf16 (transposed 256 x 4096) ---------------
__global__ __launch_bounds__(256) void k_reduce_t1t(const unsigned short* __restrict__ P,
                                                    unsigned short* __restrict__ T1T) {
  __shared__ float tile[64][65];
  const int mt = blockIdx.x, nt = blockIdx.y;
  const int t = threadIdx.x;
  #pragma unroll
  for (int e = 0; e < 16; ++e) {
    const int idx = e * 256 + t;
    const int r = idx >> 6, c = idx & 63;
    float s = 0.f;
    #pragma unroll
    for (int kt = 0; kt < 8; ++kt)
      s += bf16_bits_to_f32(
          P[(size_t)kt * 1048576 + (size_t)(mt * 64 + r) * 256 + nt * 64 + c]);
    tile[r][c] = s;
  }
  __syncthreads();
  const int nr = t >> 2, mq = (t & 3) * 16;
  unsigned short tmp[16];
  #pragma unroll
  for (int k = 0; k < 16; ++k) tmp[k] = f32_to_bf16_bits(tile[mq + k][nr]);
  unsigned short* dst = T1T + (size_t)(nt * 64 + nr) * 4096 + mt * 64 + mq;
  *(int4*)(dst) = *(const int4*)(tmp);
  *(int4*)(dst + 8) = *(const int4*)(tmp + 8);
}

// --- reduce bf16 partials + fused epilogue: out = sum P - d[row]*rm, vec x4 -
__global__ __launch_bounds__(256) void k_reduce_out(const unsigned short* __restrict__ P,
                                                    const float* __restrict__ dvec,
                                                    const float* __restrict__ rm,
                                                    float* __restrict__ out) {
  const size_t base = ((size_t)blockIdx.x * 256 + threadIdx.x) * 4;  // row*256+col
  const int row = (int)(base >> 8);
  const int col = (int)(base & 255);
  float s0 = 0.f, s1 = 0.f, s2 = 0.f, s3 = 0.f;
  #pragma unroll
  for (int kt = 0; kt < 8; ++kt) {
    ushort4v v = *(const ushort4v*)(P + (size_t)kt * 1048576 + base);
    s0 += bf16_bits_to_f32(v.x);
    s1 += bf16_bits_to_f32(v.y);
    s2 += bf16_bits_to_f32(v.z);
    s3 += bf16_bits_to_f32(v.w);
  }
  const int b = col >> 5, f = col & 31;  // 4 consecutive f within one b
  const size_t o = ((size_t)b * 4096 + row) * 32 + f;
  const float dv = dvec[row];
  const float4 rv = *(const float4*)(rm + o);
  float4 ov;
  ov.x = s0 - dv * rv.x;
  ov.y = s1 - dv * rv.y;
  ov.z = s2 - dv * rv.z;
  ov.w = s3 - dv * rv.w;
  *(float4*)(out + o) = ov;
}

extern "C" void kernel_launch(void* const* d_in, const int* in_sizes, int n_in,
                              void* d_out, int out_size, void* d_ws, size_t ws_size,
                              hipStream_t stream) {
  const float* rm = (const float*)d_in[0];   // (8, 4096, 32) fp32
  const float* adj = (const float*)d_in[1];  // (4096, 4096) fp32
  float* out = (float*)d_out;
  char* ws = (char*)d_ws;

  unsigned char* A8    = (unsigned char*)(ws);              // 16 MiB (dead after big GEMM)
  unsigned char* A8T   = (unsigned char*)(ws + 16777216);   // 16 MiB (dead after big GEMM)
  unsigned short* A2bf = (unsigned short*)(ws + 67108864);  // 32 MiB
  unsigned short* RMT  = (unsigned short*)(ws + 100663296); // 2 MiB
  unsigned short* T1T  = (unsigned short*)(ws + 102760448); // 2 MiB
  float* dvec          = (float*)(ws + 104857600);          // 16 KiB
  unsigned short* Pp   = (unsigned short*)(ws);             // 16 MiB, reuses A8

  // prep: adj->fp8 (a, at) + RMT + dvec=0, one dispatch
  k_prep<<<4608, 256, 0, stream>>>(adj, A8, A8T, rm, RMT, dvec);

  // A2 = adj @ adj  (MX-fp8, constant scale)
  k_gemm_big_fp8<<<dim3(32, 32), 256, 0, stream>>>(A8, A8T, A2bf, 4096, 4096, 4096);

  // fused: diag (triangular, 2112 blocks) + T1 split-K GEMM (1024 blocks)
  k_diag_skinny1<<<3136, 256, 0, stream>>>(A2bf, RMT, Pp, dvec);
  k_reduce_t1t<<<dim3(64, 4), 256, 0, stream>>>(Pp, T1T);

  // T2 = A2 @ T1 (split-K, bf16 partials) -> fused out = T2 - d*rm
  k_gemm_skinny<512><<<dim3(64, 2, 8), 256, 0, stream>>>(A2bf, T1T, Pp, 4096);
  k_reduce_out<<<1024, 256, 0, stream>>>(Pp, dvec, rm, out);
}

// Round 10
// 225.882 us; speedup vs baseline: 1.1639x; 1.0219x over previous
//
#include <hip/hip_runtime.h>

// ---------------------------------------------------------------------------
// SGC: out[b,i,f] = sum_{j!=i} (adj^4)[i,j] * rm[b,j,f]
//   A2   = adj @ adj          (MX-fp8 e4m3 MFMA K=128, 4096^3, const scale)
//   T1   = A2 @ RM            (split-K KC=512, bf16 partials; FUSED with diag)
//   out  = A2 @ T1 - d*rm     (split-K, bf16 partials, fused vec reduce)
//   d[i] = sum_j A2[i,j]*A2[j,i]  (triangular tile-pairs, fused into skinny1)
// Lessons encoded:
//  - A2 must be the M-side operand of the skinnies (r8); n-tile pairs of the
//    same (m,kt) are XCD-paired via bx = m*16 + n*8 + kt (round-robin i%8)
//    so the A2 slice is read once from HBM, twice from the XCD L2 (r10).
//  - Skinny blocks dispatch BEFORE diag blocks in the fused kernel: the GEMM
//    is the critical path into reduce_t1t -> skinny2 (r10).
//  - KC=512/8-way split beats 16-way (partial traffic > TLP gain, r8).
//  - LDS-free fragment-direct skinny regressed 2x (r6): keep LDS staging.
//  - fp8 LDS conflicts (8.39e6) are structural, not the critical pipe (r5).
//  - Same-address split-K atomics regressed (r3): explicit partials.
//  - Big GEMM at m148's MX-fp8 plateau (~1.7 PF): FROZEN.
// ---------------------------------------------------------------------------

typedef __attribute__((ext_vector_type(8))) __bf16 bf16x8;
typedef __attribute__((ext_vector_type(8))) int intx8;
typedef __attribute__((ext_vector_type(4))) float floatx4;
typedef __attribute__((ext_vector_type(4))) short short4v;
typedef __attribute__((ext_vector_type(4))) unsigned short ushort4v;

__device__ __forceinline__ unsigned short f32_to_bf16_bits(float f) {
  unsigned int u = __float_as_uint(f);
  u += 0x7FFFu + ((u >> 16) & 1u);  // RNE
  return (unsigned short)(u >> 16);
}
__device__ __forceinline__ float bf16_bits_to_f32(unsigned short s) {
  return __uint_as_float(((unsigned int)s) << 16);
}

// OCP e4m3fn quantization, manual RNE (unbiased). Input in [0, 448].
__device__ __forceinline__ unsigned char f32_to_e4m3(float v) {
  if (!(v > 0.f)) return 0;
  unsigned u = __float_as_uint(v);
  int e = (int)((u >> 23) & 0xFF) - 127;
  if (e >= -6) {                      // normal e4m3
    unsigned m = u & 0x7FFFFF;
    unsigned keep = m >> 20;
    unsigned rem = m & 0xFFFFF;
    keep += (rem > 0x80000u) || (rem == 0x80000u && (keep & 1u));
    if (keep == 8u) { keep = 0u; e += 1; }
    return (unsigned char)(((e + 7) << 3) | keep);
  }
  if (e < -10) return 0;
  float scaled = v * 512.f;           // 2^9
  int m4 = (int)rintf(scaled);        // RNE
  if (m4 >= 8) return 0x08;
  return (unsigned char)m4;
}

__device__ __forceinline__ void gld_lds16(const void* g, void* l) {
  __builtin_amdgcn_global_load_lds(
      (const __attribute__((address_space(1))) void*)g,
      (__attribute__((address_space(3))) void*)l, 16, 0, 0);
}

// --- fused prep: blocks [0,4096): adj fp32 -> fp8(x2^13) a + at;
//                 blocks [4096,4608): RMT[b*32+f][j] = bf16(rm[b,j,f]) + dvec=0
__global__ __launch_bounds__(256) void k_prep(const float* __restrict__ adj,
                                              unsigned char* __restrict__ a,
                                              unsigned char* __restrict__ at,
                                              const float* __restrict__ rm,
                                              unsigned short* __restrict__ rmt,
                                              float* __restrict__ dvec) {
  __shared__ __align__(16) float tile[64][65];
  const int bx = blockIdx.x;
  const int t = threadIdx.x;
  if (bx < 4096) {
    const int row0 = (bx >> 6) * 64, col0 = (bx & 63) * 64;
    const int c4 = (t & 15) * 4;
    const int r = t >> 4;
    for (int rr = 0; rr < 64; rr += 16) {
      float4 v = *(const float4*)(adj + (size_t)(row0 + r + rr) * 4096 + col0 + c4);
      tile[r + rr][c4 + 0] = v.x;
      tile[r + rr][c4 + 1] = v.y;
      tile[r + rr][c4 + 2] = v.z;
      tile[r + rr][c4 + 3] = v.w;
      unsigned char q[4];
      q[0] = f32_to_e4m3(v.x * 8192.f);
      q[1] = f32_to_e4m3(v.y * 8192.f);
      q[2] = f32_to_e4m3(v.z * 8192.f);
      q[3] = f32_to_e4m3(v.w * 8192.f);
      *(unsigned int*)(a + (size_t)(row0 + r + rr) * 4096 + col0 + c4) =
          *(const unsigned int*)q;
    }
    __syncthreads();
    for (int rr = 0; rr < 64; rr += 16) {
      const int orow = r + rr;
      unsigned char q[4];
      q[0] = f32_to_e4m3(tile[c4 + 0][orow] * 8192.f);
      q[1] = f32_to_e4m3(tile[c4 + 1][orow] * 8192.f);
      q[2] = f32_to_e4m3(tile[c4 + 2][orow] * 8192.f);
      q[3] = f32_to_e4m3(tile[c4 + 3][orow] * 8192.f);
      *(unsigned int*)(at + (size_t)(col0 + orow) * 4096 + row0 + c4) =
          *(const unsigned int*)q;
    }
  } else {
    unsigned short(*tile2)[33] = (unsigned short(*)[33])tile;
    const int idx = bx - 4096;           // [0,512)
    const int b = idx & 7;
    const int j0 = (idx >> 3) * 64;
    const int z = (idx >> 3) * 256 + t;  // dvec zeroing (first 16 j-tiles)
    if (b == 0 && z < 4096) dvec[z] = 0.f;
    #pragma unroll
    for (int p = 0; p < 2; ++p) {
      const int j = (t >> 3) + p * 32;
      const int f4 = (t & 7) * 4;
      float4 v = *(const float4*)(rm + ((size_t)b * 4096 + j0 + j) * 32 + f4);
      tile2[j][f4 + 0] = f32_to_bf16_bits(v.x);
      tile2[j][f4 + 1] = f32_to_bf16_bits(v.y);
      tile2[j][f4 + 2] = f32_to_bf16_bits(v.z);
      tile2[j][f4 + 3] = f32_to_bf16_bits(v.w);
    }
    __syncthreads();
    const int f = t >> 3, j8 = (t & 7) * 8;
    unsigned short tmp[8];
    #pragma unroll
    for (int k = 0; k < 8; ++k) tmp[k] = tile2[j8 + k][f];
    *(int4*)(rmt + ((size_t)b * 32 + f) * 4096 + j0 + j8) = *(const int4*)tmp;
  }
}

// --- big GEMM (MX-fp8): C = A @ BT^T, 128x128 tile, BK=128 (FROZEN) ---------
__global__ __launch_bounds__(256) void k_gemm_big_fp8(const unsigned char* __restrict__ A,
                                                      const unsigned char* __restrict__ BT,
                                                      unsigned short* __restrict__ C,
                                                      int M, int N, int K) {
  __shared__ __align__(16) unsigned char smA[128 * 128];
  __shared__ __align__(16) unsigned char smB[128 * 128];
  const int tid = threadIdx.x;
  const int wave = tid >> 6, lane = tid & 63;
  const int quad = lane >> 4, l16 = lane & 15;
  const int wm = (wave & 1) * 64, wn = (wave >> 1) * 64;
  const int m0 = blockIdx.x * 128, n0 = blockIdx.y * 128;
  const int srow = lane >> 3;                 // 0..7
  const int gcol = ((lane & 7) ^ srow) * 16;  // swizzled byte col

  floatx4 acc[4][4];
  #pragma unroll
  for (int i = 0; i < 4; ++i)
    #pragma unroll
    for (int j = 0; j < 4; ++j) acc[i][j] = floatx4{0.f, 0.f, 0.f, 0.f};

  for (int k0 = 0; k0 < K; k0 += 128) {
    #pragma unroll
    for (int c = 0; c < 4; ++c) {
      const int ch = wave * 4 + c;  // 16 chunks of 1KB each per operand
      const int row = ch * 8 + srow;
      gld_lds16(A + (size_t)(m0 + row) * K + k0 + gcol, smA + ch * 1024);
      gld_lds16(BT + (size_t)(n0 + row) * K + k0 + gcol, smB + ch * 1024);
    }
    __syncthreads();
    intx8 af[4], bfr[4];
    #pragma unroll
    for (int i = 0; i < 4; ++i) {
      const int row = wm + i * 16 + l16;
      const int x = l16 & 7;
      const int4 lo = *(const int4*)(smA + row * 128 + (((2 * quad) ^ x) * 16));
      const int4 hi = *(const int4*)(smA + row * 128 + (((2 * quad + 1) ^ x) * 16));
      af[i] = intx8{lo.x, lo.y, lo.z, lo.w, hi.x, hi.y, hi.z, hi.w};
    }
    #pragma unroll
    for (int j = 0; j < 4; ++j) {
      const int row = wn + j * 16 + l16;
      const int x = l16 & 7;
      const int4 lo = *(const int4*)(smB + row * 128 + (((2 * quad) ^ x) * 16));
      const int4 hi = *(const int4*)(smB + row * 128 + (((2 * quad + 1) ^ x) * 16));
      bfr[j] = intx8{lo.x, lo.y, lo.z, lo.w, hi.x, hi.y, hi.z, hi.w};
    }
    #pragma unroll
    for (int i = 0; i < 4; ++i)
      #pragma unroll
      for (int j = 0; j < 4; ++j)
        acc[i][j] = __builtin_amdgcn_mfma_scale_f32_16x16x128_f8f6f4(
            af[i], bfr[j], acc[i][j], 0, 0,      // cbsz=fp8, blgp=fp8
            0, 0x7F7F7F7F, 0, 0x7F7F7F7F);       // scales = 2^0
    __syncthreads();
  }
  const float unscale = 1.4901161193847656e-8f;  // 2^-26
  #pragma unroll
  for (int i = 0; i < 4; ++i) {
    #pragma unroll
    for (int j = 0; j < 4; ++j) {
      const int rowb = m0 + wm + i * 16 + quad * 4;
      const int col = n0 + wn + j * 16 + l16;
      #pragma unroll
      for (int r = 0; r < 4; ++r)
        C[(size_t)(rowb + r) * N + col] = f32_to_bf16_bits(acc[i][j][r] * unscale);
    }
  }
}

// --- FUSED: skinny1 (blocks [0,1024)) + diag (triangular, [1024,3136)) ------
// skinny1: T1 = A2 @ RMT^T; BM=64, BN=128, KC=512, dbuf LDS, bf16 partials
//   P[kt][4096][256]. Block map bx = m*16 + n*8 + kt: the two n-tiles of one
//   (m,kt) are 8 apart in dispatch order -> same XCD (i%8) -> shared A2 in L2.
// diag: block (I, Jo): J=(I+Jo)&63; loads A2 tile-pair, contributes to both
//   d[I-tile] and d[J-tile]. Jo==0: diagonal; Jo==32 only for I<32.
__global__ __launch_bounds__(256) void k_diag_skinny1(
    const unsigned short* __restrict__ A2,
    const unsigned short* __restrict__ RMT,
    unsigned short* __restrict__ P,
    float* __restrict__ d) {
  __shared__ __align__(16) char smem[49152];
  const int t = threadIdx.x;
  const int bx = blockIdx.x;

  if (bx >= 1024) {
    // ---------------- diag part ----------------
    constexpr int PP = 72;
    unsigned short* t1 = (unsigned short*)smem;
    unsigned short* t2 = t1 + 64 * PP;
    float* red = (float*)(smem + 18432);
    const int bd = bx - 1024;
    const int I = bd & 63;
    const int Jo = bd >> 6;  // 0..32
    if (Jo == 32 && I >= 32) return;
    const int J = (I + Jo) & 63;
    for (int c = t; c < 512; c += 256) {
      const int row = c >> 3, col = (c & 7) * 8;
      *(int4*)(t1 + row * PP + col) =
          *(const int4*)(A2 + (size_t)(I * 64 + row) * 4096 + J * 64 + col);
      if (Jo)
        *(int4*)(t2 + row * PP + col) =
            *(const int4*)(A2 + (size_t)(J * 64 + row) * 4096 + I * 64 + col);
    }
    __syncthreads();
    const unsigned short* tt2 = Jo ? t2 : t1;
    const int i = t & 63, q = t >> 6;
    float s1 = 0.f, s2 = 0.f;
    #pragma unroll
    for (int jj = 0; jj < 16; ++jj) {
      const int j = q * 16 + jj;
      s1 += bf16_bits_to_f32(t1[i * PP + j]) * bf16_bits_to_f32(tt2[j * PP + i]);
      if (Jo)
        s2 += bf16_bits_to_f32(t2[i * PP + j]) * bf16_bits_to_f32(t1[j * PP + i]);
    }
    red[t] = s1;
    __syncthreads();
    if (t < 64)
      atomicAdd(&d[I * 64 + t], red[t] + red[t + 64] + red[t + 128] + red[t + 192]);
    if (Jo) {
      __syncthreads();
      red[t] = s2;
      __syncthreads();
      if (t < 64)
        atomicAdd(&d[J * 64 + t], red[t] + red[t + 64] + red[t + 128] + red[t + 192]);
    }
    return;
  }

  // ---------------- skinny1 part ----------------
  constexpr int KC = 512;
  constexpr int NITER = KC / 64;
  const int K = 4096;
  unsigned short* smA = (unsigned short*)smem;            // [2][64*64]
  unsigned short* smB = (unsigned short*)(smem + 16384);  // [2][128*64]
  const int wave = t >> 6, lane = t & 63;
  const int quad = lane >> 4, l16 = lane & 15;
  const int kt = bx & 7;
  const int m0 = (bx >> 4) * 64;
  const int n0 = ((bx >> 3) & 1) * 128;
  const int wm = (wave & 1) * 32, wn = (wave >> 1) * 64;
  const int srow = lane >> 3;
  const int gcol = ((lane & 7) ^ srow) * 8;
  const int kbeg = kt * KC;

  floatx4 acc[2][4];
  #pragma unroll
  for (int i = 0; i < 2; ++i)
    #pragma unroll
    for (int j = 0; j < 4; ++j) acc[i][j] = floatx4{0.f, 0.f, 0.f, 0.f};

  auto stage = [&](int buf, int k0) {  // 24 chunks of 1KB (A:0-7, B:8-23)
    #pragma unroll
    for (int u = 0; u < 6; ++u) {
      const int ch = wave * 6 + u;
      if (ch < 8) {
        const int row = ch * 8 + srow;
        gld_lds16(A2 + (size_t)(m0 + row) * K + k0 + gcol,
                  smA + buf * 4096 + ch * 512);
      } else {
        const int c2 = ch - 8;
        const int row = c2 * 8 + srow;
        gld_lds16(RMT + (size_t)(n0 + row) * K + k0 + gcol,
                  smB + buf * 8192 + c2 * 512);
      }
    }
  };

  stage(0, kbeg);
  for (int it = 0; it < NITER; ++it) {
    const int buf = it & 1;
    __syncthreads();  // buf staged (drains vmcnt)
    if (it + 1 < NITER) stage(buf ^ 1, kbeg + (it + 1) * 64);  // prefetch
    #pragma unroll
    for (int kk = 0; kk < 64; kk += 32) {
      const int g8 = quad + (kk >> 3);
      bf16x8 af[2], bfr[4];
      #pragma unroll
      for (int i = 0; i < 2; ++i) {
        const int row = wm + i * 16 + l16;
        af[i] = *(const bf16x8*)(smA + buf * 4096 + row * 64 + ((g8 ^ (row & 7)) * 8));
      }
      #pragma unroll
      for (int j = 0; j < 4; ++j) {
        const int row = wn + j * 16 + l16;
        bfr[j] = *(const bf16x8*)(smB + buf * 8192 + row * 64 + ((g8 ^ (row & 7)) * 8));
      }
      #pragma unroll
      for (int i = 0; i < 2; ++i)
        #pragma unroll
        for (int j = 0; j < 4; ++j)
          acc[i][j] = __builtin_amdgcn_mfma_f32_16x16x32_bf16(af[i], bfr[j],
                                                              acc[i][j], 0, 0, 0);
    }
  }
  #pragma unroll
  for (int i = 0; i < 2; ++i) {
    #pragma unroll
    for (int j = 0; j < 4; ++j) {
      const int rowl = wm + i * 16 + quad * 4;
      const int col = n0 + wn + j * 16 + l16;
      #pragma unroll
      for (int r = 0; r < 4; ++r)
        P[(size_t)kt * 1048576 + (size_t)(m0 + rowl + r) * 256 + col] =
            f32_to_bf16_bits(acc[i][j][r]);
    }
  }
}

// --- skinny2: same GEMM structure, standalone (A=A2, BT=T1T), XCD-paired ----
template <int KC>
__global__ __launch_bounds__(256) void k_gemm_skinny(const unsigned short* __restrict__ A,
                                                     const unsigned short* __restrict__ BT,
                                                     unsigned short* __restrict__ P, int K) {
  constexpr int NITER = KC / 64;
  __shared__ __align__(16) unsigned short smA[2][64 * 64];
  __shared__ __align__(16) unsigned short smB[2][128 * 64];
  const int tid = threadIdx.x;
  const int bx = blockIdx.x;  // bx = m*16 + n*8 + kt (XCD-pairing)
  const int wave = tid >> 6, lane = tid & 63;
  const int quad = lane >> 4, l16 = lane & 15;
  const int kt = bx & 7;
  const int m0 = (bx >> 4) * 64;
  const int n0 = ((bx >> 3) & 1) * 128;
  const int wm = (wave & 1) * 32, wn = (wave >> 1) * 64;
  const int srow = lane >> 3;
  const int gcol = ((lane & 7) ^ srow) * 8;
  const int kbeg = kt * KC;

  floatx4 acc[2][4];
  #pragma unroll
  for (int i = 0; i < 2; ++i)
    #pragma unroll
    for (int j = 0; j < 4; ++j) acc[i][j] = floatx4{0.f, 0.f, 0.f, 0.f};

  auto stage = [&](int buf, int k0) {
    #pragma unroll
    for (int u = 0; u < 6; ++u) {
      const int ch = wave * 6 + u;
      if (ch < 8) {
        const int row = ch * 8 + srow;
        gld_lds16(A + (size_t)(m0 + row) * K + k0 + gcol, &smA[buf][ch * 512]);
      } else {
        const int c2 = ch - 8;
        const int row = c2 * 8 + srow;
        gld_lds16(BT + (size_t)(n0 + row) * K + k0 + gcol, &smB[buf][c2 * 512]);
      }
    }
  };

  stage(0, kbeg);
  for (int it = 0; it < NITER; ++it) {
    const int buf = it & 1;
    __syncthreads();
    if (it + 1 < NITER) stage(buf ^ 1, kbeg + (it + 1) * 64);
    #pragma unroll
    for (int kk = 0; kk < 64; kk += 32) {
      const int g8 = quad + (kk >> 3);
      bf16x8 af[2], bfr[4];
      #pragma unroll
      for (int i = 0; i < 2; ++i) {
        const int row = wm + i * 16 + l16;
        af[i] = *(const bf16x8*)(&smA[buf][row * 64 + ((g8 ^ (row & 7)) * 8)]);
      }
      #pragma unroll
      for (int j = 0; j < 4; ++j) {
        const int row = wn + j * 16 + l16;
        bfr[j] = *(const bf16x8*)(&smB[buf][row * 64 + ((g8 ^ (row & 7)) * 8)]);
      }
      #pragma unroll
      for (int i = 0; i < 2; ++i)
        #pragma unroll
        for (int j = 0; j < 4; ++j)
          acc[i][j] = __builtin_amdgcn_mfma_f32_16x16x32_bf16(af[i], bfr[j],
                                                              acc[i][j], 0, 0, 0);
    }
  }
  #pragma unroll
  for (int i = 0; i < 2; ++i) {
    #pragma unroll
    for (int j = 0; j < 4; ++j) {
      const int rowl = wm + i * 16 + quad * 4;
      const int col = n0 + wn + j * 16 + l16;
      #pragma unroll
      for (int r = 0; r < 4; ++r)
        P[((size_t)kt * 4096 + m0 + rowl + r) * 256 + col] =
            f32_to_bf16_bits(acc[i][j][r]);
    }
  }
}

// --- reduce bf16 partials -> T1T bf16 (transposed 256 x 4096) ---------------
__global__ __launch_bounds__(256) void k_reduce_t1t(const unsigned short* __restrict__ P,
                                                    unsigned short* __restrict__ T1T) {
  __shared__ float tile[64][65];
  const int mt = blockIdx.x, nt = blockIdx.y;
  const int t = threadIdx.x;
  #pragma unroll
  for (int e = 0; e < 16; ++e) {
    const int idx = e * 256 + t;
    const int r = idx >> 6, c = idx & 63;
    float s = 0.f;
    #pragma unroll
    for (int kt = 0; kt < 8; ++kt)
      s += bf16_bits_to_f32(
          P[(size_t)kt * 1048576 + (size_t)(mt * 64 + r) * 256 + nt * 64 + c]);
    tile[r][c] = s;
  }
  __syncthreads();
  const int nr = t >> 2, mq = (t & 3) * 16;
  unsigned short tmp[16];
  #pragma unroll
  for (int k = 0; k < 16; ++k) tmp[k] = f32_to_bf16_bits(tile[mq + k][nr]);
  unsigned short* dst = T1T + (size_t)(nt * 64 + nr) * 4096 + mt * 64 + mq;
  *(int4*)(dst) = *(const int4*)(tmp);
  *(int4*)(dst + 8) = *(const int4*)(tmp + 8);
}

// --- reduce bf16 partials + fused epilogue: out = sum P - d[row]*rm, vec x4 -
__global__ __launch_bounds__(256) void k_reduce_out(const unsigned short* __restrict__ P,
                                                    const float* __restrict__ dvec,
                                                    const float* __restrict__ rm,
                                                    float* __restrict__ out) {
  const size_t base = ((size_t)blockIdx.x * 256 + threadIdx.x) * 4;  // row*256+col
  const int row = (int)(base >> 8);
  const int col = (int)(base & 255);
  float s0 = 0.f, s1 = 0.f, s2 = 0.f, s3 = 0.f;
  #pragma unroll
  for (int kt = 0; kt < 8; ++kt) {
    ushort4v v = *(const ushort4v*)(P + (size_t)kt * 1048576 + base);
    s0 += bf16_bits_to_f32(v.x);
    s1 += bf16_bits_to_f32(v.y);
    s2 += bf16_bits_to_f32(v.z);
    s3 += bf16_bits_to_f32(v.w);
  }
  const int b = col >> 5, f = col & 31;  // 4 consecutive f within one b
  const size_t o = ((size_t)b * 4096 + row) * 32 + f;
  const float dv = dvec[row];
  const float4 rv = *(const float4*)(rm + o);
  float4 ov;
  ov.x = s0 - dv * rv.x;
  ov.y = s1 - dv * rv.y;
  ov.z = s2 - dv * rv.z;
  ov.w = s3 - dv * rv.w;
  *(float4*)(out + o) = ov;
}

extern "C" void kernel_launch(void* const* d_in, const int* in_sizes, int n_in,
                              void* d_out, int out_size, void* d_ws, size_t ws_size,
                              hipStream_t stream) {
  const float* rm = (const float*)d_in[0];   // (8, 4096, 32) fp32
  const float* adj = (const float*)d_in[1];  // (4096, 4096) fp32
  float* out = (float*)d_out;
  char* ws = (char*)d_ws;

  unsigned char* A8    = (unsigned char*)(ws);              // 16 MiB (dead after big GEMM)
  unsigned char* A8T   = (unsigned char*)(ws + 16777216);   // 16 MiB (dead after big GEMM)
  unsigned short* A2bf = (unsigned short*)(ws + 67108864);  // 32 MiB
  unsigned short* RMT  = (unsigned short*)(ws + 100663296); // 2 MiB
  unsigned short* T1T  = (unsigned short*)(ws + 102760448); // 2 MiB
  float* dvec          = (float*)(ws + 104857600);          // 16 KiB
  unsigned short* Pp   = (unsigned short*)(ws);             // 16 MiB, reuses A8

  // prep: adj->fp8 (a, at) + RMT + dvec=0, one dispatch
  k_prep<<<4608, 256, 0, stream>>>(adj, A8, A8T, rm, RMT, dvec);

  // A2 = adj @ adj  (MX-fp8, constant scale)
  k_gemm_big_fp8<<<dim3(32, 32), 256, 0, stream>>>(A8, A8T, A2bf, 4096, 4096, 4096);

  // fused: T1 split-K GEMM (1024 blocks, first) + diag (2112 blocks, filler)
  k_diag_skinny1<<<3136, 256, 0, stream>>>(A2bf, RMT, Pp, dvec);
  k_reduce_t1t<<<dim3(64, 4), 256, 0, stream>>>(Pp, T1T);

  // T2 = A2 @ T1 (split-K, XCD-paired blocks) -> fused out = T2 - d*rm
  k_gemm_skinny<512><<<1024, 256, 0, stream>>>(A2bf, T1T, Pp, 4096);
  k_reduce_out<<<1024, 256, 0, stream>>>(Pp, dvec, rm, out);
}